// Round 11
// baseline (132.683 us; speedup 1.0000x reference)
//
#include <hip/hip_runtime.h>
#include <math.h>

#define D 8
#define K 32
constexpr int BLOCK = 256;
constexpr int ROWS  = 4;                       // pipeline stages (1 row each)
constexpr int GRID  = 2048;                    // GRID*BLOCK*ROWS == N (full residency)
constexpr int NWAVE = BLOCK / 64;

typedef float vf4 __attribute__((ext_vector_type(4)));

// numpy pairwise-sum tree for n=8: ((p0+p1)+(p2+p3))+((p4+p5)+(p6+p7)),
// all roundings explicit (no contraction, no reassociation).
__device__ __forceinline__ float pairwise8_sq(const float* v) {
    float p[D];
    #pragma unroll
    for (int d = 0; d < D; ++d) p[d] = __fmul_rn(v[d], v[d]);
    return __fadd_rn(
        __fadd_rn(__fadd_rn(p[0], p[1]), __fadd_rn(p[2], p[3])),
        __fadd_rn(__fadd_rn(p[4], p[5]), __fadd_rn(p[6], p[7])));
}

__global__ __launch_bounds__(BLOCK) void vq_main(
        const float* __restrict__ z,
        const float* __restrict__ cb,
        float* __restrict__ zq,
        float* __restrict__ part_sum,          // [GRID]
        unsigned int* __restrict__ part_hist,  // [K][GRID]
        int n)
{
    __shared__ float cb_s[K * D];              // epilogue gather only
    __shared__ float c2_s[K];
    __shared__ unsigned int h_s[K];
    __shared__ float wsum[NWAVE];

    const int tid = threadIdx.x;
    if (tid < K * D) cb_s[tid] = cb[tid];
    if (tid < K) h_s[tid] = 0u;
    __syncthreads();
    if (tid < K) c2_s[tid] = pairwise8_sq(&cb_s[tid * D]);  // np.sum(cb*cb,1)
    __syncthreads();

    // block owns 1024 contiguous rows; thread owns base + g*256, g=0..3
    const int base = blockIdx.x * (BLOCK * ROWS) + tid;

    float lsum = 0.f;

    // ---- software-pipelined row loop: prefetch g+1 while computing g ----
    float4 na, nb;                              // prefetch regs
    {
        const float4* zp = (const float4*)(z + (size_t)base * D);
        na = zp[0];
        nb = zp[1];
    }

    #pragma unroll
    for (int g = 0; g < ROWS; ++g) {
        float zr[D] = {na.x, na.y, na.z, na.w, nb.x, nb.y, nb.z, nb.w};

        // issue next row's loads BEFORE the compute chain — overlaps the
        // ~900-cycle argmin with the next VMEM round-trip
        if (g + 1 < ROWS) {
            const float4* zp =
                (const float4*)(z + (size_t)(base + (g + 1) * BLOCK) * D);
            na = zp[0];
            nb = zp[1];
        }

        float z2 = pairwise8_sq(zr);            // np.sum(z*z,1)

        float best = 3.4e38f;
        int   bidx = 0;
        #pragma unroll 4
        for (int k = 0; k < K; ++k) {
            // OpenBLAS sgemm K=8: sequential FMA chain from 0 — bit-exact;
            // cb[k*D+d] is wave-uniform -> SGPR operand (no LDS/VMEM per lane)
            float dot = 0.f;
            #pragma unroll
            for (int d = 0; d < D; ++d)
                dot = __builtin_fmaf(zr[d], cb[k * D + d], dot);
            // (z2 - 2*dot) + c2, left-to-right, no contraction
            float dist = __fadd_rn(__fsub_rn(z2, __fmul_rn(2.0f, dot)), c2_s[k]);
            if (dist < best) { best = dist; bidx = k; }  // first-index ties
        }

        atomicAdd(&h_s[bidx], 1u);

        float o[D];
        #pragma unroll
        for (int d = 0; d < D; ++d) {
            float cq   = cb_s[bidx * D + d];    // LDS gather (divergent idx)
            float diff = __fsub_rn(cq, zr[d]);  // (z_q - z)
            lsum += diff * diff;
            o[d] = __fadd_rn(zr[d], diff);      // z + (z_q - z): ST rounding
        }
        // plain stores: L2 merges interleaved halves (R9: WRITE at ideal 67 MB);
        // fire-and-forget — drains while the next group computes
        vf4* op = (vf4*)(zq + (size_t)(base + g * BLOCK) * D);
        op[0] = (vf4){o[0], o[1], o[2], o[3]};
        op[1] = (vf4){o[4], o[5], o[6], o[7]};
    }

    // wave(64) shuffle reduction of squared-error sum
    #pragma unroll
    for (int off = 32; off > 0; off >>= 1)
        lsum += __shfl_down(lsum, off, 64);
    if ((tid & 63) == 0) wsum[tid >> 6] = lsum;
    __syncthreads();
    if (tid == 0) {
        float t = 0.f;
        #pragma unroll
        for (int w = 0; w < NWAVE; ++w) t += wsum[w];
        part_sum[blockIdx.x] = t;
    }
    if (tid < K) part_hist[(size_t)tid * GRID + blockIdx.x] = h_s[tid];
}

__global__ __launch_bounds__(1024) void vq_final(
        const float* __restrict__ part_sum,
        const unsigned int* __restrict__ part_hist,
        float* __restrict__ out, long long nd, int n)
{
    __shared__ double red[16];
    __shared__ unsigned int hsum[K];
    __shared__ double ent_s[K];
    const int tid = threadIdx.x;

    // total squared error: GRID partials, f64 accumulate
    double s = 0.0;
    for (int i = tid; i < GRID; i += 1024) s += (double)part_sum[i];
    #pragma unroll
    for (int off = 32; off > 0; off >>= 1) s += __shfl_down(s, off, 64);
    if ((tid & 63) == 0) red[tid >> 6] = s;

    // histogram: 32 threads per bin k, coalesced strided loads, subgroup reduce
    {
        const int k = tid >> 5, j = tid & 31;
        const unsigned int* p = part_hist + (size_t)k * GRID;
        unsigned int c = 0;
        for (int i = j; i < GRID; i += 32) c += p[i];
        #pragma unroll
        for (int off = 16; off > 0; off >>= 1) c += __shfl_down(c, off, 32);
        if (j == 0) hsum[k] = c;
    }
    __syncthreads();

    if (tid < K) {
        double p = (double)hsum[tid] / (double)n;
        ent_s[tid] = p * log(p + 1e-10);
    }
    __syncthreads();

    if (tid == 0) {
        double S = 0.0;
        #pragma unroll
        for (int w = 0; w < 16; ++w) S += red[w];
        double ent = 0.0;
        for (int k = 0; k < K; ++k) ent += ent_s[k];
        out[nd]     = (float)(1.25 * S / (double)nd);
        out[nd + 1] = (float)exp(-ent);
    }
}

extern "C" void kernel_launch(void* const* d_in, const int* in_sizes, int n_in,
                              void* d_out, int out_size, void* d_ws, size_t ws_size,
                              hipStream_t stream)
{
    const float* z  = (const float*)d_in[0];
    const float* cb = (const float*)d_in[1];
    float* out      = (float*)d_out;

    const int n = in_sizes[0] / D;             // 2,097,152 == GRID*BLOCK*ROWS
    const long long nd = (long long)n * D;

    // ws layout: [0, GRID*4) float part_sum; [32768, +K*GRID*4) uint part_hist
    float*        part_sum  = (float*)d_ws;
    unsigned int* part_hist = (unsigned int*)((char*)d_ws + 32768);

    vq_main<<<GRID, BLOCK, 0, stream>>>(z, cb, out, part_sum, part_hist, n);
    vq_final<<<1, 1024, 0, stream>>>(part_sum, part_hist, out, nd, n);
}